// Round 8
// baseline (78.726 us; speedup 1.0000x reference)
//
#include <hip/hip_runtime.h>

// Problem constants (match the reference)
#define T_DIM 160
#define B_DIM 64
#define C_DIM 6625
#define S_DIM 25
#define L_DIM 51            // 2*S+1
#define J_DIM 26            // distinct class slots: blank + 25 labels
#define TJ    (T_DIM * J_DIM)        // 4160
#define NEGV  (-1.0e30f)
#define LOG2E 1.4426950408889634f
#define LN2   0.6931471805599453f
#define GCHUNK  16
#define NGCHUNK (T_DIM / GCHUNK)     // 10
#define MAGIC 0x5A17C0DEF00DFACEull  // != 0xAAAA.. poison; CAS-consumed to 0

// lane l gets x from lane l-1 via DPP wave_shr:1 (~5 cy vs ~35 cy ds_bpermute).
// Lane 0 receives `fill` through the DPP old-operand (bound_ctrl=0).
__device__ __forceinline__ float wave_shr1(float x, float fill) {
    return __int_as_float(__builtin_amdgcn_update_dpp(
        __float_as_int(fill), __float_as_int(x),
        0x138 /* wave_shr:1 */, 0xF, 0xF, false));
}

// ---------------------------------------------------------------------------
// Single-node uberkernel. 640 blocks: blk = b*10 + c.
//   c=1..9 : gather chunk c of batch b -> emit_ws, release flags[b][c]=MAGIC.
//   c=0    : gather chunk 0 -> LDS, consume 9 flags (CAS MAGIC->0, acquire),
//            burst chunks 1..9 from ws, run wave-0 alpha chain (R7-proven),
//            publish per_b[b] via done[b]=MAGIC.
//   b=0,c=0: additionally consume all 64 done flags, reduce, store out[0].
// Flag protocol is self-resetting (consume=CAS to 0; producer atomicExch to
// MAGIC) -> deterministic across graph replays; all 640 blocks co-resident
// (<< capacity) so spin-wait cannot deadlock.
// ---------------------------------------------------------------------------
__global__ __launch_bounds__(256)
void ctc_uber(const float* __restrict__ preds,     // [T,B,C]
              const int*   __restrict__ targets,   // [B,S]
              const int*   __restrict__ tlen,      // [B]
              float*       __restrict__ emit_ws,   // [B,T,26]
              unsigned long long* __restrict__ flags,  // [B,10]
              unsigned long long* __restrict__ done,   // [B]
              float*       __restrict__ per_b,     // [B]
              float*       __restrict__ out)       // scalar
{
    const int blk = blockIdx.x;
    const int b   = blk / NGCHUNK;
    const int c   = blk - b * NGCHUNK;
    const int tid = threadIdx.x;

    __shared__ float emit_s[TJ];                 // 16640 B (alpha blocks only)
    __shared__ int   cls_s[J_DIM];

    if (tid < J_DIM) cls_s[tid] = (tid == 0) ? 0 : targets[b * S_DIM + tid - 1];
    __syncthreads();

    const size_t row = (size_t)B_DIM * C_DIM;
    const float* pbase = preds + (size_t)b * C_DIM;

    if (c != 0) {
        // ---- producer: gather chunk c into ws, then release flag ----
        const int t0 = c * GCHUNK;
        float* wsb = emit_ws + (size_t)b * TJ;
        for (int f = tid; f < GCHUNK * J_DIM; f += 256) {
            int tl = f / J_DIM;
            int j  = f - tl * J_DIM;
            wsb[(t0 + tl) * J_DIM + j] =
                pbase[(size_t)(t0 + tl) * row + cls_s[j]] * LOG2E;
        }
        __threadfence();                          // release: data before flag
        __syncthreads();                          // all threads' stores fenced
        if (tid == 0) atomicExch(&flags[b * NGCHUNK + c], MAGIC);
        return;
    }

    // ---- alpha block: chunk 0 straight into LDS ----
    for (int f = tid; f < GCHUNK * J_DIM; f += 256) {
        int tl = f / J_DIM;
        int j  = f - tl * J_DIM;
        emit_s[f] = pbase[(size_t)tl * row + cls_s[j]] * LOG2E;
    }
    // consume flags 1..9 (lanes of wave 1 spin independently)
    if (tid >= 64 && tid < 64 + NGCHUNK - 1) {
        unsigned long long* fl = &flags[b * NGCHUNK + (tid - 63)];
        while (atomicCAS(fl, MAGIC, 0ull) != MAGIC)
            __builtin_amdgcn_s_sleep(2);
        __threadfence();                          // acquire: flag before data
    }
    __syncthreads();
    // burst chunks 1..9 from ws (936 float4s over 256 threads)
    {
        const float4* src = (const float4*)(emit_ws + (size_t)b * TJ + GCHUNK * J_DIM);
        float4*       dst = (float4*)(emit_s + GCHUNK * J_DIM);
        for (int i = tid; i < (TJ - GCHUNK * J_DIM) / 4; i += 256) dst[i] = src[i];
    }
    __syncthreads();

    if (tid < 64) {
        // ---- R7-proven chain: lane l = lattice position, log2 domain ----
        const int  l      = tid;
        const bool active = (l < L_DIM);
        const int  j      = active ? ((l & 1) ? (l >> 1) + 1 : 0) : 0;
        const int* tg     = targets + b * S_DIM;

        float mask3 = NEGV;             // additive skip mask: 0 if skip allowed
        if (active && (l & 1) && l >= 3) {
            int i = l >> 1;
            if (tg[i] != tg[i - 1]) mask3 = 0.0f;
        }

        float alpha = NEGV;             // log2-domain alpha
        if (l == 0) alpha = emit_s[0];
        if (l == 1) alpha = emit_s[1];

        #pragma unroll 8
        for (int t = 1; t < T_DIM; ++t) {
            float e  = active ? emit_s[t * J_DIM + j] : 0.0f;
            float a2 = wave_shr1(alpha, NEGV);       // alpha[l-1]
            float a3 = wave_shr1(a2, NEGV) + mask3;  // alpha[l-2] (masked)
            float m  = fmaxf(fmaxf(alpha, a2), a3);  // v_max3
            float s  = __builtin_amdgcn_exp2f(alpha - m)
                     + __builtin_amdgcn_exp2f(a2 - m)
                     + __builtin_amdgcn_exp2f(a3 - m);
            alpha = m + __builtin_amdgcn_logf(s) + e;
        }

        const int len = tlen[b];
        const int idx = 2 * len;                     // in [10, 50]
        float l_last = __shfl(alpha, idx, 64);
        float l_prev = __shfl(alpha, idx - 1, 64);
        if (tid == 0) {
            float m   = fmaxf(l_last, l_prev);
            float r2  = m + __builtin_amdgcn_logf(
                             __builtin_amdgcn_exp2f(l_last - m)
                           + __builtin_amdgcn_exp2f(l_prev - m));
            float nll = -r2 * LN2;
            per_b[b] = (nll >= 1e29f) ? 0.0f : nll / (float)len;
            __threadfence();                         // release per_b
            atomicExch(&done[b], MAGIC);
        }

        // ---- final reduce on block (b=0,c=0) ----
        if (b == 0) {
            bool got = false;
            unsigned long long* fl = &done[tid];
            while (!got) {
                if (atomicCAS(fl, MAGIC, 0ull) == MAGIC) got = true;
                else __builtin_amdgcn_s_sleep(2);
            }
            __threadfence();                         // acquire all per_b
            float v = per_b[tid];
            #pragma unroll
            for (int off = 32; off > 0; off >>= 1)
                v += __shfl_down(v, off, 64);
            if (tid == 0) out[0] = v * (1.0f / B_DIM);
        }
    }
}

// ---------------------------------------------------------------------------
// Fallback: R7's proven two-node path (if ws too small for flags layout).
// ---------------------------------------------------------------------------
__global__ __launch_bounds__(256)
void ctc_gather(const float* __restrict__ preds, const int* __restrict__ targets,
                float* __restrict__ emit_ws, float* __restrict__ out)
{
    const int b = blockIdx.x, c = blockIdx.y, tid = threadIdx.x;
    if (b == 0 && c == 0 && tid == 0) out[0] = 0.0f;
    __shared__ int cls_s[J_DIM];
    if (tid < J_DIM) cls_s[tid] = (tid == 0) ? 0 : targets[b * S_DIM + tid - 1];
    __syncthreads();
    const int t0 = c * GCHUNK;
    for (int f = tid; f < GCHUNK * J_DIM; f += 256) {
        int tl = f / J_DIM, j = f - tl * J_DIM, t = t0 + tl;
        float v = preds[((size_t)t * B_DIM + b) * C_DIM + cls_s[j]];
        emit_ws[(size_t)b * TJ + (size_t)t * J_DIM + j] = v * LOG2E;
    }
}

__global__ __launch_bounds__(256)
void ctc_alpha(const float* __restrict__ emit_ws, const int* __restrict__ targets,
               const int* __restrict__ tlen, float* __restrict__ out)
{
    const int b = blockIdx.x, tid = threadIdx.x;
    __shared__ float emit_s[TJ];
    {
        const float4* src = (const float4*)(emit_ws + (size_t)b * TJ);
        float4*       dst = (float4*)emit_s;
        for (int i = tid; i < TJ / 4; i += 256) dst[i] = src[i];
    }
    __syncthreads();
    if (tid >= 64) return;
    const int  l      = tid;
    const bool active = (l < L_DIM);
    const int  j      = active ? ((l & 1) ? (l >> 1) + 1 : 0) : 0;
    const int* tg     = targets + b * S_DIM;
    float mask3 = NEGV;
    if (active && (l & 1) && l >= 3) {
        int i = l >> 1;
        if (tg[i] != tg[i - 1]) mask3 = 0.0f;
    }
    float alpha = NEGV;
    if (l == 0) alpha = emit_s[0];
    if (l == 1) alpha = emit_s[1];
    #pragma unroll 8
    for (int t = 1; t < T_DIM; ++t) {
        float e  = active ? emit_s[t * J_DIM + j] : 0.0f;
        float a2 = wave_shr1(alpha, NEGV);
        float a3 = wave_shr1(a2, NEGV) + mask3;
        float m  = fmaxf(fmaxf(alpha, a2), a3);
        float s  = __builtin_amdgcn_exp2f(alpha - m)
                 + __builtin_amdgcn_exp2f(a2 - m)
                 + __builtin_amdgcn_exp2f(a3 - m);
        alpha = m + __builtin_amdgcn_logf(s) + e;
    }
    const int len = tlen[b];
    const int idx = 2 * len;
    float l_last = __shfl(alpha, idx, 64);
    float l_prev = __shfl(alpha, idx - 1, 64);
    if (tid == 0) {
        float m   = fmaxf(l_last, l_prev);
        float r2  = m + __builtin_amdgcn_logf(
                         __builtin_amdgcn_exp2f(l_last - m)
                       + __builtin_amdgcn_exp2f(l_prev - m));
        float nll = -r2 * LN2;
        float per = (nll >= 1e29f) ? 0.0f : nll / (float)len;
        atomicAdd(out, per * (1.0f / B_DIM));
    }
}

extern "C" void kernel_launch(void* const* d_in, const int* in_sizes, int n_in,
                              void* d_out, int out_size, void* d_ws, size_t ws_size,
                              hipStream_t stream)
{
    const float* preds   = (const float*)d_in[0];   // [T,B,C] fp32
    const int*   targets = (const int*)d_in[1];     // [B,S]
    const int*   tlen    = (const int*)d_in[2];     // [B]
    float* out = (float*)d_out;                     // scalar

    const size_t emit_bytes = (size_t)B_DIM * TJ * sizeof(float);     // 1064960
    const size_t flag_bytes = (size_t)B_DIM * NGCHUNK * 8;            // 5120
    const size_t done_bytes = (size_t)B_DIM * 8;                      // 512
    const size_t perb_bytes = (size_t)B_DIM * sizeof(float);          // 256
    const size_t ws_needed  = emit_bytes + flag_bytes + done_bytes + perb_bytes;

    if (ws_size >= ws_needed) {
        float* emit_ws = (float*)d_ws;
        unsigned long long* flags = (unsigned long long*)((char*)d_ws + emit_bytes);
        unsigned long long* done  = flags + (size_t)B_DIM * NGCHUNK;
        float* per_b = (float*)(done + B_DIM);
        ctc_uber<<<B_DIM * NGCHUNK, 256, 0, stream>>>(
            preds, targets, tlen, emit_ws, flags, done, per_b, out);
    } else if (ws_size >= emit_bytes) {
        float* emit_ws = (float*)d_ws;
        dim3 ggrid(B_DIM, NGCHUNK);
        ctc_gather<<<ggrid, 256, 0, stream>>>(preds, targets, emit_ws, out);
        ctc_alpha<<<B_DIM, 256, 0, stream>>>(emit_ws, targets, tlen, out);
    }
}

// Round 10
// 18.447 us; speedup vs baseline: 4.2677x; 4.2677x over previous
//
#include <hip/hip_runtime.h>

// Problem constants (match the reference)
#define T_DIM 160
#define B_DIM 64
#define C_DIM 6625
#define S_DIM 25
#define L_DIM 51            // 2*S+1
#define J_DIM 26            // distinct class slots: blank + 25 labels
#define TJ    (T_DIM * J_DIM)        // 4160
#define NEGV  (-1.0e30f)
#define LOG2E 1.4426950408889634f
#define LN2   0.6931471805599453f
#define GCHUNK  16
#define NGCHUNK (T_DIM / GCHUNK)     // 10

// lane l gets x from lane l-1 via DPP wave_shr:1. Lane 0 receives `fill`.
__device__ __forceinline__ float wave_shr1(float x, float fill) {
    return __int_as_float(__builtin_amdgcn_update_dpp(
        __float_as_int(fill), __float_as_int(x),
        0x138 /* wave_shr:1 */, 0xF, 0xF, false));
}

// running max with a DPP-moved copy; ctrl must be an immediate -> template arg
template <int CTRL>
__device__ __forceinline__ float dpp_max(float x) {
    return fmaxf(x, __int_as_float(__builtin_amdgcn_update_dpp(
        __float_as_int(x), __float_as_int(x), CTRL, 0xF, 0xF, false)));
}

// ---------------------------------------------------------------------------
// Node 1: wide gather across all CUs. Block (b,c) fetches the 26 needed
// classes for t in [16c,16c+16) and writes LINEAR-domain emissions
// E = exp2(v*log2e) = e^v to emit_ws[b][t][26]. Also zeroes out[0].
// ---------------------------------------------------------------------------
__global__ __launch_bounds__(256)
void ctc_gather(const float* __restrict__ preds,     // [T,B,C]
                const int*   __restrict__ targets,   // [B,S]
                float*       __restrict__ emit_ws,   // [B,T,26] linear domain
                float*       __restrict__ out)       // scalar, zeroed here
{
    const int b   = blockIdx.x;
    const int c   = blockIdx.y;
    const int tid = threadIdx.x;

    if (b == 0 && c == 0 && tid == 0) out[0] = 0.0f;

    __shared__ int cls_s[J_DIM];
    if (tid < J_DIM) cls_s[tid] = (tid == 0) ? 0 : targets[b * S_DIM + tid - 1];
    __syncthreads();

    const int t0 = c * GCHUNK;
    for (int f = tid; f < GCHUNK * J_DIM; f += 256) {
        int tl = f / J_DIM;
        int j  = f - tl * J_DIM;
        int t  = t0 + tl;
        float v = preds[((size_t)t * B_DIM + b) * C_DIM + cls_s[j]];
        emit_ws[(size_t)b * TJ + (size_t)t * J_DIM + j] =
            __builtin_amdgcn_exp2f(v * LOG2E);       // e^v, off critical path
    }
}

// ---------------------------------------------------------------------------
// Node 2: linear-domain recurrence. One block per batch element; 256 threads
// burst the 16.6 KB slab into LDS, then wave 0 runs the 159-step chain:
//   alpha = (alpha + alpha[l-1] + alpha[l-2]*mask) * E     (no transcendentals)
// with an exact power-of-two renormalization every 8 steps (integer exponent
// offset), and a single log2 at the end.
// ---------------------------------------------------------------------------
__global__ __launch_bounds__(256)
void ctc_alpha(const float* __restrict__ emit_ws,    // [B,T,26] linear
               const int*   __restrict__ targets,    // [B,S]
               const int*   __restrict__ tlen,       // [B]
               float*       __restrict__ out)        // scalar (zeroed by node 1)
{
    const int b   = blockIdx.x;
    const int tid = threadIdx.x;

    __shared__ float emit_s[TJ];                     // 16640 B

    {   // contiguous burst: 1040 float4s over 256 threads
        const float4* src = (const float4*)(emit_ws + (size_t)b * TJ);
        float4*       dst = (float4*)emit_s;
        for (int i = tid; i < TJ / 4; i += 256) dst[i] = src[i];
    }
    __syncthreads();
    if (tid >= 64) return;                           // chain on wave 0 only

    const int  l      = tid;                         // lattice position
    const bool active = (l < L_DIM);
    const int  j      = active ? ((l & 1) ? (l >> 1) + 1 : 0) : 0;
    const int* tg     = targets + b * S_DIM;

    float mask3 = 0.0f;                 // multiplicative skip mask
    if (active && (l & 1) && l >= 3) {
        int i = l >> 1;
        if (tg[i] != tg[i - 1]) mask3 = 1.0f;
    }
    const float act = active ? 1.0f : 0.0f;          // inactive lanes stay 0

    float alpha = 0.0f;                              // linear-domain alpha
    if (l == 0) alpha = emit_s[0];
    if (l == 1) alpha = emit_s[1];
    int off = 0;                                     // accumulated log2 offset

#define STEP(t_) {                                                    \
        float e  = emit_s[(t_) * J_DIM + j] * act;                    \
        float a2 = wave_shr1(alpha, 0.0f);                            \
        float a3 = wave_shr1(a2, 0.0f);                               \
        alpha = fmaf(a3, mask3, alpha + a2) * e;                      \
    }
#define RENORM() {                                                    \
        float w = alpha;                                              \
        w = dpp_max<0x111>(w);  /* row_shr:1  */                      \
        w = dpp_max<0x112>(w);  /* row_shr:2  */                      \
        w = dpp_max<0x114>(w);  /* row_shr:4  */                      \
        w = dpp_max<0x118>(w);  /* row_shr:8  */                      \
        w = dpp_max<0x142>(w);  /* row_bcast:15 */                    \
        w = dpp_max<0x143>(w);  /* row_bcast:31 -> lane63 = wave max */\
        int mb = __builtin_amdgcn_readlane(__float_as_int(w), 63);    \
        int ex = ((mb >> 23) & 0xFF) - 127;   /* floor(log2(max)) */  \
        alpha *= __int_as_float((127 - ex) << 23);  /* exact 2^-ex */ \
        off += ex;                                                    \
    }

    // steps t = 1..7, then renorm; 19 more segments of 8 steps
    #pragma unroll
    for (int t = 1; t < 8; ++t) STEP(t);
    RENORM();
    #pragma unroll 1
    for (int seg = 1; seg < 20; ++seg) {
        const int t0 = seg * 8;
        #pragma unroll
        for (int k = 0; k < 8; ++k) STEP(t0 + k);
        if (seg != 19) RENORM();
    }
#undef STEP
#undef RENORM

    // nll = -ln2 * (log2(a_last + a_prev) + off)
    const int len = tlen[b];
    const int idx = 2 * len;                         // in [10, 50]
    float a_last = __shfl(alpha, idx, 64);
    float a_prev = __shfl(alpha, idx - 1, 64);
    if (tid == 0) {
        float s   = a_last + a_prev;                 // 0 -> log2 = -inf
        float nll = -(__builtin_amdgcn_logf(s) + (float)off) * LN2;
        float per = (nll >= 1e29f) ? 0.0f : nll / (float)len;
        atomicAdd(out, per * (1.0f / B_DIM));
    }
}

// ---------------------------------------------------------------------------
// Fallback (R5-proven fused log-domain kernel) if ws is too small.
// ---------------------------------------------------------------------------
#define CHUNK  32
#define NCHUNK (T_DIM / CHUNK)   // 5
__global__ __launch_bounds__(256)
void ctc_alpha_fused(const float* __restrict__ preds,
                     const int*   __restrict__ targets,
                     const int*   __restrict__ tlen,
                     float*       __restrict__ out)
{
    const int b   = blockIdx.x;
    const int tid = threadIdx.x;
    __shared__ float emit_s[T_DIM * J_DIM];
    __shared__ int   cls_s[J_DIM];
    if (tid < J_DIM) cls_s[tid] = (tid == 0) ? 0 : targets[b * S_DIM + tid - 1];
    __syncthreads();
    const size_t row = (size_t)B_DIM * C_DIM;
    const float* pb  = preds + (size_t)b * C_DIM;
    for (int f = tid; f < CHUNK * J_DIM; f += 256) {
        int t = f / J_DIM;
        int j = f - t * J_DIM;
        emit_s[f] = pb[(size_t)t * row + cls_s[j]] * LOG2E;
    }
    __syncthreads();
    const int  l      = tid;
    const bool active = (l < L_DIM);
    const int  j      = active ? ((l & 1) ? (l >> 1) + 1 : 0) : 0;
    float mask3 = NEGV;
    if (active && (l & 1) && l >= 3) {
        int i = l >> 1;
        if (targets[b * S_DIM + i] != targets[b * S_DIM + i - 1]) mask3 = 0.0f;
    }
    float alpha = NEGV;
    if (l == 0) alpha = emit_s[0];
    if (l == 1) alpha = emit_s[1];
    for (int c = 0; c < NCHUNK; ++c) {
        if (tid >= 64) {
            if (c + 1 < NCHUNK) {
                const int base = (c + 1) * CHUNK * J_DIM;
                const int t0   = (c + 1) * CHUNK;
                for (int f = tid - 64; f < CHUNK * J_DIM; f += 192) {
                    int tt = f / J_DIM;
                    int jj = f - tt * J_DIM;
                    emit_s[base + f] =
                        pb[(size_t)(t0 + tt) * row + cls_s[jj]] * LOG2E;
                }
            }
        } else {
            const int cbase = c * CHUNK * J_DIM;
            #pragma unroll
            for (int k = 0; k < CHUNK; ++k) {
                if (c == 0 && k == 0) continue;
                float e  = active ? emit_s[cbase + k * J_DIM + j] : 0.0f;
                float a2 = wave_shr1(alpha, NEGV);
                float a3 = wave_shr1(a2, NEGV) + mask3;
                float m  = fmaxf(fmaxf(alpha, a2), a3);
                float s  = __builtin_amdgcn_exp2f(alpha - m)
                         + __builtin_amdgcn_exp2f(a2 - m)
                         + __builtin_amdgcn_exp2f(a3 - m);
                alpha = m + __builtin_amdgcn_logf(s) + e;
            }
        }
        __syncthreads();
    }
    if (tid < 64) {
        const int len = tlen[b];
        const int idx = 2 * len;
        float l_last = __shfl(alpha, idx, 64);
        float l_prev = __shfl(alpha, idx - 1, 64);
        if (tid == 0) {
            float m   = fmaxf(l_last, l_prev);
            float r2  = m + __builtin_amdgcn_logf(
                             __builtin_amdgcn_exp2f(l_last - m)
                           + __builtin_amdgcn_exp2f(l_prev - m));
            float nll = -r2 * LN2;
            float per = (nll >= 1e29f) ? 0.0f : nll / (float)len;
            atomicAdd(out, per * (1.0f / B_DIM));
        }
    }
}

extern "C" void kernel_launch(void* const* d_in, const int* in_sizes, int n_in,
                              void* d_out, int out_size, void* d_ws, size_t ws_size,
                              hipStream_t stream)
{
    const float* preds   = (const float*)d_in[0];   // [T,B,C] fp32
    const int*   targets = (const int*)d_in[1];     // [B,S]
    const int*   tlen    = (const int*)d_in[2];     // [B]
    float* out = (float*)d_out;                     // scalar

    const size_t ws_needed = (size_t)B_DIM * TJ * sizeof(float);
    if (ws_size >= ws_needed) {
        float* emit_ws = (float*)d_ws;
        dim3 ggrid(B_DIM, NGCHUNK);
        ctc_gather<<<ggrid, 256, 0, stream>>>(preds, targets, emit_ws, out);
        ctc_alpha<<<B_DIM, 256, 0, stream>>>(emit_ws, targets, tlen, out);
    } else {
        (void)hipMemsetAsync(out, 0, sizeof(float), stream);
        ctc_alpha_fused<<<B_DIM, 256, 0, stream>>>(preds, targets, tlen, out);
    }
}